// Round 1
// 396.132 us; speedup vs baseline: 1.0397x; 1.0397x over previous
//
#include <hip/hip_runtime.h>
#include <hip/hip_bf16.h>
#include <hip/hip_fp16.h>

#define ETA 0.15f
#define LAM 0.05f

typedef unsigned int uint32;
typedef __attribute__((ext_vector_type(8))) short short8;
typedef __attribute__((ext_vector_type(4))) float floatx4;
typedef __attribute__((ext_vector_type(2))) uint32 uint32x2;
typedef __attribute__((ext_vector_type(4))) _Float16 half4;

static const int BSZ = 32, LL = 8192, DD = 64;
static const int RTOT = BSZ * LL; // 262144 rows

// workspace layout (bytes)
static const size_t MU_BYTES = (size_t)RTOT * DD * 2;   // mu as fp16
static const size_t W1T_OFF  = MU_BYTES;                // [256][128] bf16 (n-major)
static const size_t W2T_OFF  = W1T_OFF + 256 * 128 * 2; // [64][256] bf16
static const size_t WQT_OFF  = W2T_OFF + 64 * 256 * 2;  // [64][64] bf16

__device__ __forceinline__ unsigned short f2bf(float f) {
    uint32 u = __builtin_bit_cast(uint32, f);
    uint32 r = (u + 0x7FFFu + ((u >> 16) & 1u)) >> 16;
    return (unsigned short)r;
}
// packed RNE f32x2 -> bf16x2 (1 VALU op; same rounding as f2bf)
__device__ __forceinline__ uint32 cvtpk(float lo, float hi) {
    uint32 r;
    asm("v_cvt_pk_bf16_f32 %0, %1, %2" : "=v"(r) : "v"(lo), "v"(hi));
    return r;
}
__device__ __forceinline__ float fast_softplus(float x) {
    return fmaxf(x, 0.f) + __logf(1.f + __expf(-fabsf(x)));
}
__device__ __forceinline__ float fast_tanh(float x) {
    float t = __expf(-2.f * fabsf(x));
    float r = (1.f - t) / (1.f + t);
    return copysignf(r, x);
}

// ---------------- prep: zero energy, transpose weights to bf16 ----------------
__global__ void prep_kernel(const float* __restrict__ W1, const float* __restrict__ W2,
                            const float* __restrict__ Wq,
                            unsigned short* __restrict__ w1t, unsigned short* __restrict__ w2t,
                            unsigned short* __restrict__ wqt, float* __restrict__ energy) {
    int tid = blockIdx.x * blockDim.x + threadIdx.x;
    int nth = gridDim.x * blockDim.x;
    for (int i = tid; i < 256 * 128; i += nth) { int n = i >> 7, k = i & 127; w1t[i] = f2bf(W1[k * 256 + n]); }
    for (int i = tid; i < 64 * 256; i += nth) { int n = i >> 8, k = i & 255; w2t[i] = f2bf(W2[k * 64 + n]); }
    for (int i = tid; i < 64 * 64;  i += nth) { int n = i >> 6, k = i & 63;  wqt[i] = f2bf(Wq[k * 64 + n]); }
    if (tid < 32) energy[tid] = 0.f;
}

// ---------------- MLP ----------------
// 64 rows/block, 4 waves. LDS = 32768 B (Zs [64][256] XOR-swizzled overlays the
// staging region) -> up to 5 blocks/CU. cvt_pk packed bf16 conversion everywhere;
// Zs swizzle: 16B-block index ^ ((row>>1)&7) -> conflict-free writes AND b128 reads.
__global__ __launch_bounds__(256) void mlp_kernel(
    const float* __restrict__ A, const float* __restrict__ B, const float* __restrict__ Q,
    const float* __restrict__ b1, const float* __restrict__ b2, const float* __restrict__ bq,
    const unsigned short* __restrict__ w1t, const unsigned short* __restrict__ w2t,
    const unsigned short* __restrict__ wqt, _Float16* __restrict__ mu_out) {
    __shared__ char lds[32768];
    unsigned short* Xs = (unsigned short*)(lds);          // [64][136] bf16 (staging phase)
    unsigned short* Qs = (unsigned short*)(lds + 17408);  // [64][72]  bf16 (staging phase)
    unsigned short* Zs = (unsigned short*)(lds);          // [64][256] bf16 swizzled (after barrier 2)

    const int tid = threadIdx.x;
    const int lane = tid & 63;
    const int w = tid >> 6;
    const int q4 = lane >> 4;
    const int l16 = lane & 15;
    const int rowbase = blockIdx.x * 64;

    // prefetch GEMM3 weights + biases before the barrier (global, no LDS dep)
    short8 wqf[2];
#pragma unroll
    for (int kt = 0; kt < 2; kt++)
        wqf[kt] = *(const short8*)&wqt[(w * 16 + l16) * 64 + kt * 32 + q4 * 8];
    float b1v4[4];
#pragma unroll
    for (int nt = 0; nt < 4; nt++) b1v4[nt] = b1[(w * 4 + nt) * 16 + l16];
    const int ocol = w * 16 + l16;
    const float b2v = b2[ocol], bqv = bq[ocol];

    // stage X = [A|B] as bf16 (float4 loads, packed converts)
    uint32* Xu = (uint32*)Xs; // row stride 68 uints
    for (int i = tid; i < 64 * 32; i += 256) {
        int r = i >> 5, c = i & 31;
        const float* src = (c < 16) ? (A + (size_t)(rowbase + r) * 64 + c * 4)
                                    : (B + (size_t)(rowbase + r) * 64 + (c - 16) * 4);
        floatx4 v = *(const floatx4*)src;
        uint32x2 u; u.x = cvtpk(v.x, v.y); u.y = cvtpk(v.z, v.w);
        *(uint32x2*)&Xu[r * 68 + c * 2] = u;
    }
    // stage Q
    uint32* Qu = (uint32*)Qs; // row stride 36 uints
    for (int i = tid; i < 64 * 16; i += 256) {
        int r = i >> 4, c = i & 15;
        floatx4 v = *(const floatx4*)(Q + (size_t)(rowbase + r) * 64 + c * 4);
        uint32x2 u; u.x = cvtpk(v.x, v.y); u.y = cvtpk(v.z, v.w);
        *(uint32x2*)&Qu[r * 36 + c * 2] = u;
    }
    __syncthreads();

    // GEMM3: gate_pre = q @ Wq (wave owns out cols w*16..w*16+15); result held in regs
    floatx4 acc3[4];
#pragma unroll
    for (int m = 0; m < 4; m++) acc3[m] = (floatx4){0.f, 0.f, 0.f, 0.f};
    __builtin_amdgcn_s_setprio(1);
#pragma unroll
    for (int m = 0; m < 4; m++)
#pragma unroll
        for (int kt = 0; kt < 2; kt++) {
            short8 aq = *(const short8*)&Qs[(m * 16 + l16) * 72 + kt * 32 + q4 * 8];
            acc3[m] = __builtin_amdgcn_mfma_f32_16x16x32_bf16(aq, wqf[kt], acc3[m], 0, 0, 0);
        }
    __builtin_amdgcn_s_setprio(0);
    // preload X fragments (4 m-tiles x 4 k-tiles) so Xs region can be reused
    short8 ax[4][4];
#pragma unroll
    for (int m = 0; m < 4; m++)
#pragma unroll
        for (int kt = 0; kt < 4; kt++)
            ax[m][kt] = *(const short8*)&Xs[(m * 16 + l16) * 136 + kt * 32 + q4 * 8];
    __syncthreads(); // all reads of Xs/Qs done; Zs may now overlay

    // GEMM1: Z = relu(X @ W1 + b1), wave computes col stripe [w*64, w*64+64)
#pragma unroll
    for (int nt = 0; nt < 4; nt++) {
        const int ng = w * 4 + nt;
        short8 wf[4];
#pragma unroll
        for (int kt = 0; kt < 4; kt++)
            wf[kt] = *(const short8*)&w1t[(ng * 16 + l16) * 128 + kt * 32 + q4 * 8];
        floatx4 acc[4];
#pragma unroll
        for (int m = 0; m < 4; m++) acc[m] = (floatx4){0.f, 0.f, 0.f, 0.f};
        __builtin_amdgcn_s_setprio(1);
#pragma unroll
        for (int kt = 0; kt < 4; kt++)
#pragma unroll
            for (int m = 0; m < 4; m++)
                acc[m] = __builtin_amdgcn_mfma_f32_16x16x32_bf16(ax[m][kt], wf[kt], acc[m], 0, 0, 0);
        __builtin_amdgcn_s_setprio(0);
        const int col = ng * 16 + l16;
        const int c8 = col >> 3, c7 = col & 7;
        const float b1v = b1v4[nt];
#pragma unroll
        for (int m = 0; m < 4; m++) {
            float z0 = fmaxf(acc[m][0] + b1v, 0.f);
            float z1 = fmaxf(acc[m][1] + b1v, 0.f);
            float z2 = fmaxf(acc[m][2] + b1v, 0.f);
            float z3 = fmaxf(acc[m][3] + b1v, 0.f);
            uint32 u01 = cvtpk(z0, z1), u23 = cvtpk(z2, z3);
            const int row0 = m * 16 + q4 * 4;
            // swizzled: (row>>1)&7 = q4*2 for rows {row0,row0+1}, q4*2+1 for {row0+2,row0+3}
            const int a0 = row0 * 256 + ((c8 ^ (q4 * 2)) << 3) + c7;
            const int a2 = (row0 + 2) * 256 + ((c8 ^ (q4 * 2 + 1)) << 3) + c7;
            Zs[a0]       = (unsigned short)u01;
            Zs[a0 + 256] = (unsigned short)(u01 >> 16);
            Zs[a2]       = (unsigned short)u23;
            Zs[a2 + 256] = (unsigned short)(u23 >> 16);
        }
    }
    // preload GEMM2 B-frags while waiting on barrier
    short8 w2f[8];
#pragma unroll
    for (int kt = 0; kt < 8; kt++)
        w2f[kt] = *(const short8*)&w2t[(w * 16 + l16) * 256 + kt * 32 + q4 * 8];
    __syncthreads();

    // GEMM2: mu_pre = Z @ W2 (wave owns out cols w*16..w*16+15)
    floatx4 acc2[4];
#pragma unroll
    for (int m = 0; m < 4; m++) acc2[m] = (floatx4){0.f, 0.f, 0.f, 0.f};
    const int sxr = (l16 >> 1) & 7; // read swizzle for row=l16 (m*16 doesn't affect low 3 bits)
    __builtin_amdgcn_s_setprio(1);
#pragma unroll
    for (int m = 0; m < 4; m++)
#pragma unroll
        for (int kt = 0; kt < 8; kt++) {
            short8 az = *(const short8*)&Zs[(m * 16 + l16) * 256 + (((kt * 4 + q4) ^ sxr) << 3)];
            acc2[m] = __builtin_amdgcn_mfma_f32_16x16x32_bf16(az, w2f[kt], acc2[m], 0, 0, 0);
        }
    __builtin_amdgcn_s_setprio(0);
    // epilogue
#pragma unroll
    for (int m = 0; m < 4; m++)
#pragma unroll
        for (int r = 0; r < 4; r++) {
            int row = m * 16 + q4 * 4 + r;
            float sp = fast_softplus(acc2[m][r] + b2v);
            float g = fast_tanh(acc3[m][r] + bqv);
            float mu = sp * (1.f + 0.5f * g);
            mu_out[(size_t)(rowbase + row) * 64 + ocol] = (_Float16)mu;
        }
}

// ---------------- K=6 iterations + energy (sum/difference form) ----------------
// Linearity: with s=A+B, d=A-B the step is d <- (1-2*eta*mu)*d, s unchanged; both
// then smoothed. hA=(s+d)/2, hB=(s-d)/2. Saves 15 of 20 vec-ops/row/iter on the
// step. Thread (c4=tid&15, g=tid>>4) owns cols c4*4..+3 of rows g*5..g*5+4 in an
// 80-row window (halo 8/side; erosion 6 < 8). 1 barrier/iter via parity-double-
// buffered boundary exchange (32KB LDS).
__global__ __launch_bounds__(256) void iter_kernel(
    const float* __restrict__ A, const float* __restrict__ B, const _Float16* __restrict__ mu_ws,
    float* __restrict__ outA, float* __restrict__ outB, float* __restrict__ energy) {
    __shared__ float ex[2][4][16][64]; // [parity][sTop,sBot,dTop,dBot][g][col]
    __shared__ float esm[4];
    const int tid = threadIdx.x;
    const int c4 = tid & 15;
    const int g = tid >> 4;
    const int b = blockIdx.y;
    const int s0 = blockIdx.x * 64;
    const size_t bbase = (size_t)b * 8192;
    const int r0 = g * 5;

    floatx4 sv[5], dv[5], fv[5];
#pragma unroll
    for (int i = 0; i < 5; i++) {
        int gl = (s0 + r0 + i + 8192 - 8) & 8191; // window starts at s0-8 (circular)
        size_t base = (bbase + gl) * 64 + c4 * 4;
        floatx4 av = *(const floatx4*)(A + base);
        floatx4 bv = *(const floatx4*)(B + base);
        half4 m4 = *(const half4*)(mu_ws + base);
        floatx4 mu = __builtin_convertvector(m4, floatx4);
        sv[i] = av + bv;
        dv[i] = av - bv;
        fv[i] = 1.f - (2.f * ETA) * mu;
    }
    for (int it = 0; it < 6; it++) {
        // step in s/d form: d *= f  (s unchanged)
#pragma unroll
        for (int i = 0; i < 5; i++) dv[i] *= fv[i];
        const int p = it & 1;
        *(floatx4*)&ex[p][0][g][c4 * 4] = sv[0];
        *(floatx4*)&ex[p][1][g][c4 * 4] = sv[4];
        *(floatx4*)&ex[p][2][g][c4 * 4] = dv[0];
        *(floatx4*)&ex[p][3][g][c4 * 4] = dv[4];
        __syncthreads();
        floatx4 sUp = (g > 0)  ? *(const floatx4*)&ex[p][1][g - 1][c4 * 4] : sv[0];
        floatx4 sDn = (g < 15) ? *(const floatx4*)&ex[p][0][g + 1][c4 * 4] : sv[4];
        floatx4 dUp = (g > 0)  ? *(const floatx4*)&ex[p][3][g - 1][c4 * 4] : dv[0];
        floatx4 dDn = (g < 15) ? *(const floatx4*)&ex[p][2][g + 1][c4 * 4] : dv[4];
        // smooth s (rolling 3-point)
        floatx4 prev = sUp, cur = sv[0];
#pragma unroll
        for (int i = 0; i < 5; i++) {
            floatx4 nxt = (i < 4) ? sv[i + 1] : sDn;
            sv[i] = cur - LAM * (2.f * cur - prev - nxt);
            prev = cur; cur = nxt;
        }
        // smooth d
        prev = dUp; cur = dv[0];
#pragma unroll
        for (int i = 0; i < 5; i++) {
            floatx4 nxt = (i < 4) ? dv[i + 1] : dDn;
            dv[i] = cur - LAM * (2.f * cur - prev - nxt);
            prev = cur; cur = nxt;
        }
    }
    // store interior rows (window rows 8..71) + energy partial
    float e = 0.f;
#pragma unroll
    for (int i = 0; i < 5; i++) {
        int wr = r0 + i;
        if (wr >= 8 && wr < 72) {
            floatx4 d = dv[i];
            floatx4 q = (1.f - fv[i]) * d * d; // (1-f) = 2*eta*mu
            e += q.x + q.y + q.z + q.w;
            size_t gidx = (bbase + s0 + (wr - 8)) * 64 + c4 * 4;
            *(floatx4*)(outA + gidx) = (sv[i] + d) * 0.5f;
            *(floatx4*)(outB + gidx) = (sv[i] - d) * 0.5f;
        }
    }
    e *= 0.25f / ETA; // sum(2*eta*mu*d^2) * 0.25/eta = 0.5*sum(mu*d^2)
#pragma unroll
    for (int off = 32; off > 0; off >>= 1) e += __shfl_down(e, off, 64);
    if ((tid & 63) == 0) esm[tid >> 6] = e;
    __syncthreads();
    if (tid == 0) atomicAdd(energy + b, esm[0] + esm[1] + esm[2] + esm[3]);
}

extern "C" void kernel_launch(void* const* d_in, const int* in_sizes, int n_in,
                              void* d_out, int out_size, void* d_ws, size_t ws_size,
                              hipStream_t stream) {
    const float* A  = (const float*)d_in[0];
    const float* B  = (const float*)d_in[1];
    const float* Q  = (const float*)d_in[2];
    const float* W1 = (const float*)d_in[3];
    const float* b1 = (const float*)d_in[4];
    const float* W2 = (const float*)d_in[5];
    const float* b2 = (const float*)d_in[6];
    const float* Wq = (const float*)d_in[7];
    const float* bq = (const float*)d_in[8];

    float* outA = (float*)d_out;
    float* outB = outA + (size_t)RTOT * 64;
    float* energy = outB + (size_t)RTOT * 64;

    char* ws = (char*)d_ws;
    _Float16* mu_ws = (_Float16*)ws;
    unsigned short* w1t = (unsigned short*)(ws + W1T_OFF);
    unsigned short* w2t = (unsigned short*)(ws + W2T_OFF);
    unsigned short* wqt = (unsigned short*)(ws + WQT_OFF);

    hipLaunchKernelGGL(prep_kernel, dim3(64), dim3(256), 0, stream,
                       W1, W2, Wq, w1t, w2t, wqt, energy);
    hipLaunchKernelGGL(mlp_kernel, dim3(RTOT / 64), dim3(256), 0, stream,
                       A, B, Q, b1, b2, bq, w1t, w2t, wqt, mu_ws);
    hipLaunchKernelGGL(iter_kernel, dim3(LL / 64, BSZ), dim3(256), 0, stream,
                       A, B, mu_ws, outA, outB, energy);
}

// Round 2
// 346.594 us; speedup vs baseline: 1.1883x; 1.1429x over previous
//
#include <hip/hip_runtime.h>
#include <hip/hip_fp16.h>

#define ETA 0.15f
#define LAM 0.05f

typedef unsigned int uint32;
typedef __attribute__((ext_vector_type(8))) short short8;
typedef __attribute__((ext_vector_type(4))) float floatx4;
typedef __attribute__((ext_vector_type(2))) uint32 uint32x2;
typedef __attribute__((ext_vector_type(4))) _Float16 half4;

static const int BSZ = 32, LL = 8192, DD = 64;
static const int RTOT = BSZ * LL; // 262144 rows

// workspace layout (bytes): transposed bf16 weights only (mu no longer hits HBM)
static const size_t W1T_OFF = 0;                        // [256][128] bf16 (n-major)
static const size_t W2T_OFF = W1T_OFF + 256 * 128 * 2;  // [64][256] bf16
static const size_t WQT_OFF = W2T_OFF + 64 * 256 * 2;   // [64][64] bf16

__device__ __forceinline__ unsigned short f2bf(float f) {
    uint32 u = __builtin_bit_cast(uint32, f);
    uint32 r = (u + 0x7FFFu + ((u >> 16) & 1u)) >> 16;
    return (unsigned short)r;
}
// packed RNE f32x2 -> bf16x2 (1 VALU op; same rounding as f2bf)
__device__ __forceinline__ uint32 cvtpk(float lo, float hi) {
    uint32 r;
    asm("v_cvt_pk_bf16_f32 %0, %1, %2" : "=v"(r) : "v"(lo), "v"(hi));
    return r;
}
__device__ __forceinline__ float fast_softplus(float x) {
    return fmaxf(x, 0.f) + __logf(1.f + __expf(-fabsf(x)));
}
__device__ __forceinline__ float fast_tanh(float x) {
    float t = __expf(-2.f * fabsf(x));
    float r = (1.f - t) / (1.f + t);
    return copysignf(r, x);
}

// ---------------- prep: zero energy, transpose weights to bf16 ----------------
__global__ void prep_kernel(const float* __restrict__ W1, const float* __restrict__ W2,
                            const float* __restrict__ Wq,
                            unsigned short* __restrict__ w1t, unsigned short* __restrict__ w2t,
                            unsigned short* __restrict__ wqt, float* __restrict__ energy) {
    int tid = blockIdx.x * blockDim.x + threadIdx.x;
    int nth = gridDim.x * blockDim.x;
    for (int i = tid; i < 256 * 128; i += nth) { int n = i >> 7, k = i & 127; w1t[i] = f2bf(W1[k * 256 + n]); }
    for (int i = tid; i < 64 * 256; i += nth) { int n = i >> 8, k = i & 255; w2t[i] = f2bf(W2[k * 64 + n]); }
    for (int i = tid; i < 64 * 64;  i += nth) { int n = i >> 6, k = i & 63;  wqt[i] = f2bf(Wq[k * 64 + n]); }
    if (tid < 32) energy[tid] = 0.f;
}

// ---------------- fused MLP + K=6 iterations + energy ----------------
// One block = one 64-row output window, 80-row halo'd compute window (halo 8/side,
// erosion 6 < 8). Phase 1 stages A,B,Q once (A,B kept fp32 in registers in iter
// layout), phase 2 runs the 3 GEMMs on 80 rows with SWAPPED mfma operands
// (mfma(w, x): thread holds 4 consecutive output COLS -> 8B vector Z/mu stores,
// all LDS strides == 4 mod 32 dwords -> 2-way-or-free banks), phase 3 hands mu
// through LDS and runs the 6 stencil iterations from registers (s/d form).
// LDS peak 64000 B (Zs overlays Qs; mu/ex overlay Xs/Zs) -> 2 blocks/CU.
__global__ __launch_bounds__(256, 2) void fused_kernel(
    const float* __restrict__ A, const float* __restrict__ B, const float* __restrict__ Q,
    const float* __restrict__ b1, const float* __restrict__ b2, const float* __restrict__ bq,
    const unsigned short* __restrict__ w1t, const unsigned short* __restrict__ w2t,
    const unsigned short* __restrict__ wqt,
    float* __restrict__ outA, float* __restrict__ outB, float* __restrict__ energy) {
    __shared__ char lds[64048];
    unsigned short* Xs = (unsigned short*)(lds);          // [80][136] bf16  @ [0, 21760)
    unsigned short* Qs = (unsigned short*)(lds + 21760);  // [80][72]  bf16  @ [21760, 33280)
    unsigned short* Zs = (unsigned short*)(lds + 21760);  // [80][264] bf16  @ [21760, 64000) (overlays Qs after B1)
    _Float16* muS = (_Float16*)(lds);                     // [80][68]  fp16  @ [0, 10880)     (overlays Xs after B2)
    float* exb = (float*)(lds + 11264);                   // [2][4][16][64] f32 @ [11264, 44032)
    float* esm = (float*)(lds + 44032);                   // [4] f32

    const int tid = threadIdx.x;
    const int lane = tid & 63;
    const int w = tid >> 6;       // wave id (MLP: owns hidden stripe w*64.., mu cols w*16..)
    const int q4 = lane >> 4;
    const int l16 = lane & 15;
    const int g = tid >> 4;       // iter layout: row group (5 rows each)
    const int c4 = tid & 15;      // iter layout: col quad
    const int bb = blockIdx.y;
    const int s0 = blockIdx.x * 64;
    const size_t bbase = (size_t)bb * LL;

    // ---- prefetch weights/biases (global, no LDS dep) ----
    short8 wqf[2];
#pragma unroll
    for (int kt = 0; kt < 2; kt++)
        wqf[kt] = *(const short8*)&wqt[(w * 16 + l16) * 64 + kt * 32 + q4 * 8];
    floatx4 b1q[4];
#pragma unroll
    for (int ht = 0; ht < 4; ht++) b1q[ht] = *(const floatx4*)&b1[w * 64 + ht * 16 + q4 * 4];
    const floatx4 b2q = *(const floatx4*)&b2[w * 16 + q4 * 4];
    const floatx4 bqq = *(const floatx4*)&bq[w * 16 + q4 * 4];

    // ---- phase 1: stage X=[A|B],Q as bf16; keep A,B fp32 in regs (iter layout) ----
    floatx4 av[5], bv[5];
    uint32* Xu = (uint32*)Xs; // row stride 68 uints
    uint32* Qu = (uint32*)Qs; // row stride 36 uints
#pragma unroll
    for (int i = 0; i < 5; i++) {
        int wr = g * 5 + i;
        int gl = (s0 + wr + LL - 8) & (LL - 1); // window starts at s0-8 (circular)
        size_t base = (bbase + gl) * 64 + c4 * 4;
        av[i] = *(const floatx4*)(A + base);
        bv[i] = *(const floatx4*)(B + base);
        floatx4 qv = *(const floatx4*)(Q + base);
        uint32x2 ua; ua.x = cvtpk(av[i].x, av[i].y); ua.y = cvtpk(av[i].z, av[i].w);
        uint32x2 ub; ub.x = cvtpk(bv[i].x, bv[i].y); ub.y = cvtpk(bv[i].z, bv[i].w);
        uint32x2 uq; uq.x = cvtpk(qv.x, qv.y);       uq.y = cvtpk(qv.z, qv.w);
        *(uint32x2*)&Xu[wr * 68 + c4 * 2] = ua;
        *(uint32x2*)&Xu[wr * 68 + 32 + c4 * 2] = ub;
        *(uint32x2*)&Qu[wr * 36 + c4 * 2] = uq;
    }
    __syncthreads(); // B0: staging complete

    // ---- GEMM3 (swapped): acc3[nt][r] = gate_pre[row=nt*16+l16][col=w*16+q4*4+r] ----
    floatx4 acc3[5];
#pragma unroll
    for (int nt = 0; nt < 5; nt++) acc3[nt] = (floatx4){0.f, 0.f, 0.f, 0.f};
    __builtin_amdgcn_s_setprio(1);
#pragma unroll
    for (int nt = 0; nt < 5; nt++)
#pragma unroll
        for (int kt = 0; kt < 2; kt++) {
            short8 aq = *(const short8*)&Qs[(nt * 16 + l16) * 72 + kt * 32 + q4 * 8];
            acc3[nt] = __builtin_amdgcn_mfma_f32_16x16x32_bf16(wqf[kt], aq, acc3[nt], 0, 0, 0);
        }
    __builtin_amdgcn_s_setprio(0);
    // preload X fragments (B-operand) so GEMM1 needs no Xs reads
    short8 ax[5][4];
#pragma unroll
    for (int nt = 0; nt < 5; nt++)
#pragma unroll
        for (int kt = 0; kt < 4; kt++)
            ax[nt][kt] = *(const short8*)&Xs[(nt * 16 + l16) * 136 + kt * 32 + q4 * 8];
    __syncthreads(); // B1: Qs reads done; Zs may overlay

    // ---- GEMM1 (swapped): Z[row][hcol], wave owns hidden stripe w*64..w*64+63 ----
#pragma unroll
    for (int ht = 0; ht < 4; ht++) {
        short8 wf[4];
#pragma unroll
        for (int kt = 0; kt < 4; kt++)
            wf[kt] = *(const short8*)&w1t[(w * 64 + ht * 16 + l16) * 128 + kt * 32 + q4 * 8];
        floatx4 acc[5];
#pragma unroll
        for (int nt = 0; nt < 5; nt++) acc[nt] = (floatx4){0.f, 0.f, 0.f, 0.f};
        __builtin_amdgcn_s_setprio(1);
#pragma unroll
        for (int kt = 0; kt < 4; kt++)
#pragma unroll
            for (int nt = 0; nt < 5; nt++)
                acc[nt] = __builtin_amdgcn_mfma_f32_16x16x32_bf16(wf[kt], ax[nt][kt], acc[nt], 0, 0, 0);
        __builtin_amdgcn_s_setprio(0);
#pragma unroll
        for (int nt = 0; nt < 5; nt++) {
            float z0 = fmaxf(acc[nt][0] + b1q[ht].x, 0.f);
            float z1 = fmaxf(acc[nt][1] + b1q[ht].y, 0.f);
            float z2 = fmaxf(acc[nt][2] + b1q[ht].z, 0.f);
            float z3 = fmaxf(acc[nt][3] + b1q[ht].w, 0.f);
            uint32x2 uz; uz.x = cvtpk(z0, z1); uz.y = cvtpk(z2, z3);
            *(uint32x2*)&Zs[(nt * 16 + l16) * 264 + w * 64 + ht * 16 + q4 * 4] = uz;
        }
    }
    // preload GEMM2 A-frags while waiting on barrier
    short8 w2f[8];
#pragma unroll
    for (int kt = 0; kt < 8; kt++)
        w2f[kt] = *(const short8*)&w2t[(w * 16 + l16) * 256 + kt * 32 + q4 * 8];
    __syncthreads(); // B2: Zs complete

    // ---- GEMM2 (swapped): acc2[nt][r] = mu_pre[row=nt*16+l16][col=w*16+q4*4+r] ----
    floatx4 acc2[5];
#pragma unroll
    for (int nt = 0; nt < 5; nt++) acc2[nt] = (floatx4){0.f, 0.f, 0.f, 0.f};
    __builtin_amdgcn_s_setprio(1);
#pragma unroll
    for (int nt = 0; nt < 5; nt++)
#pragma unroll
        for (int kt = 0; kt < 8; kt++) {
            short8 az = *(const short8*)&Zs[(nt * 16 + l16) * 264 + kt * 32 + q4 * 8];
            acc2[nt] = __builtin_amdgcn_mfma_f32_16x16x32_bf16(w2f[kt], az, acc2[nt], 0, 0, 0);
        }
    __builtin_amdgcn_s_setprio(0);
    // epilogue: mu -> LDS (fp16, 8B vector stores; muS overlays dead Xs region)
#pragma unroll
    for (int nt = 0; nt < 5; nt++) {
        half4 h;
#pragma unroll
        for (int r = 0; r < 4; r++) {
            float sp = fast_softplus(acc2[nt][r] + ((const float*)&b2q)[r]);
            float gt = fast_tanh(acc3[nt][r] + ((const float*)&bqq)[r]);
            h[r] = (_Float16)(sp * (1.f + 0.5f * gt));
        }
        *(half4*)&muS[(nt * 16 + l16) * 68 + w * 16 + q4 * 4] = h;
    }
    __syncthreads(); // B3: mu ready

    // ---- phase 3: K=6 iterations in s/d form, all in registers ----
    floatx4 sv[5], dv[5], fv[5];
#pragma unroll
    for (int i = 0; i < 5; i++) {
        sv[i] = av[i] + bv[i];
        dv[i] = av[i] - bv[i];
        half4 m4 = *(const half4*)&muS[(g * 5 + i) * 68 + c4 * 4];
        fv[i] = 1.f - (2.f * ETA) * __builtin_convertvector(m4, floatx4);
    }
#define EX(p, t, gg) (exb + (((p) * 4 + (t)) * 16 + (gg)) * 64 + c4 * 4)
    for (int it = 0; it < 6; it++) {
#pragma unroll
        for (int i = 0; i < 5; i++) dv[i] *= fv[i];
        const int p = it & 1;
        *(floatx4*)EX(p, 0, g) = sv[0];
        *(floatx4*)EX(p, 1, g) = sv[4];
        *(floatx4*)EX(p, 2, g) = dv[0];
        *(floatx4*)EX(p, 3, g) = dv[4];
        __syncthreads();
        floatx4 sUp = (g > 0)  ? *(const floatx4*)EX(p, 1, g - 1) : sv[0];
        floatx4 sDn = (g < 15) ? *(const floatx4*)EX(p, 0, g + 1) : sv[4];
        floatx4 dUp = (g > 0)  ? *(const floatx4*)EX(p, 3, g - 1) : dv[0];
        floatx4 dDn = (g < 15) ? *(const floatx4*)EX(p, 2, g + 1) : dv[4];
        floatx4 prev = sUp, cur = sv[0];
#pragma unroll
        for (int i = 0; i < 5; i++) {
            floatx4 nxt = (i < 4) ? sv[i + 1] : sDn;
            sv[i] = cur - LAM * (2.f * cur - prev - nxt);
            prev = cur; cur = nxt;
        }
        prev = dUp; cur = dv[0];
#pragma unroll
        for (int i = 0; i < 5; i++) {
            floatx4 nxt = (i < 4) ? dv[i + 1] : dDn;
            dv[i] = cur - LAM * (2.f * cur - prev - nxt);
            prev = cur; cur = nxt;
        }
    }
#undef EX
    // ---- store interior rows (window rows 8..71) + energy ----
    float e = 0.f;
#pragma unroll
    for (int i = 0; i < 5; i++) {
        int wr = g * 5 + i;
        if (wr >= 8 && wr < 72) {
            floatx4 d = dv[i];
            floatx4 qv = (1.f - fv[i]) * d * d; // (1-f) = 2*eta*mu
            e += qv.x + qv.y + qv.z + qv.w;
            size_t gidx = (bbase + s0 + (wr - 8)) * 64 + c4 * 4;
            *(floatx4*)(outA + gidx) = (sv[i] + d) * 0.5f;
            *(floatx4*)(outB + gidx) = (sv[i] - d) * 0.5f;
        }
    }
    e *= 0.25f / ETA; // sum(2*eta*mu*d^2) * 0.25/eta = 0.5*sum(mu*d^2)
#pragma unroll
    for (int off = 32; off > 0; off >>= 1) e += __shfl_down(e, off, 64);
    if ((tid & 63) == 0) esm[tid >> 6] = e;
    __syncthreads();
    if (tid == 0) atomicAdd(energy + bb, esm[0] + esm[1] + esm[2] + esm[3]);
}

extern "C" void kernel_launch(void* const* d_in, const int* in_sizes, int n_in,
                              void* d_out, int out_size, void* d_ws, size_t ws_size,
                              hipStream_t stream) {
    const float* A  = (const float*)d_in[0];
    const float* B  = (const float*)d_in[1];
    const float* Q  = (const float*)d_in[2];
    const float* W1 = (const float*)d_in[3];
    const float* b1 = (const float*)d_in[4];
    const float* W2 = (const float*)d_in[5];
    const float* b2 = (const float*)d_in[6];
    const float* Wq = (const float*)d_in[7];
    const float* bq = (const float*)d_in[8];

    float* outA = (float*)d_out;
    float* outB = outA + (size_t)RTOT * 64;
    float* energy = outB + (size_t)RTOT * 64;

    char* ws = (char*)d_ws;
    unsigned short* w1t = (unsigned short*)(ws + W1T_OFF);
    unsigned short* w2t = (unsigned short*)(ws + W2T_OFF);
    unsigned short* wqt = (unsigned short*)(ws + WQT_OFF);

    hipLaunchKernelGGL(prep_kernel, dim3(64), dim3(256), 0, stream,
                       W1, W2, Wq, w1t, w2t, wqt, energy);
    hipLaunchKernelGGL(fused_kernel, dim3(LL / 64, BSZ), dim3(256), 0, stream,
                       A, B, Q, b1, b2, bq, w1t, w2t, wqt, outA, outB, energy);
}

// Round 3
// 333.260 us; speedup vs baseline: 1.2358x; 1.0400x over previous
//
#include <hip/hip_runtime.h>
#include <hip/hip_fp16.h>

#define ETA 0.15f
#define LAM 0.05f

typedef unsigned int uint32;
typedef __attribute__((ext_vector_type(8))) short short8;
typedef __attribute__((ext_vector_type(4))) float floatx4;
typedef __attribute__((ext_vector_type(2))) uint32 uint32x2;
typedef __attribute__((ext_vector_type(4))) _Float16 half4;

static const int BSZ = 32, LL = 8192, DD = 64;
static const int RTOT = BSZ * LL; // 262144 rows

// 13-tap coefficients of S^6, S = (1-2*lam)I + lam*(R+R^-1), lam=0.05
// ((0.9 + 0.05(x+1/x))^6), exact in double, rounded to float:
#define SC0 0.5811044375f
#define SC1 0.182631375f
#define SC2 0.024907734375f
#define SC3 0.0018309375f
#define SC4 7.603125e-5f
#define SC5 1.6875e-6f
#define SC6 1.5625e-8f

// workspace layout (bytes): transposed bf16 weights only
static const size_t W1T_OFF = 0;                        // [256][128] bf16 (n-major)
static const size_t W2T_OFF = W1T_OFF + 256 * 128 * 2;  // [64][256] bf16
static const size_t WQT_OFF = W2T_OFF + 64 * 256 * 2;   // [64][64] bf16

__device__ __forceinline__ unsigned short f2bf(float f) {
    uint32 u = __builtin_bit_cast(uint32, f);
    uint32 r = (u + 0x7FFFu + ((u >> 16) & 1u)) >> 16;
    return (unsigned short)r;
}
// packed RNE f32x2 -> bf16x2 (1 VALU op; same rounding as f2bf)
__device__ __forceinline__ uint32 cvtpk(float lo, float hi) {
    uint32 r;
    asm("v_cvt_pk_bf16_f32 %0, %1, %2" : "=v"(r) : "v"(lo), "v"(hi));
    return r;
}
__device__ __forceinline__ float fast_softplus(float x) {
    return fmaxf(x, 0.f) + __logf(1.f + __expf(-fabsf(x)));
}
__device__ __forceinline__ float fast_tanh(float x) {
    float t = __expf(-2.f * fabsf(x));
    float r = (1.f - t) / (1.f + t);
    return copysignf(r, x);
}

// ---------------- prep: zero energy, transpose weights to bf16 ----------------
__global__ void prep_kernel(const float* __restrict__ W1, const float* __restrict__ W2,
                            const float* __restrict__ Wq,
                            unsigned short* __restrict__ w1t, unsigned short* __restrict__ w2t,
                            unsigned short* __restrict__ wqt, float* __restrict__ energy) {
    int tid = blockIdx.x * blockDim.x + threadIdx.x;
    int nth = gridDim.x * blockDim.x;
    for (int i = tid; i < 256 * 128; i += nth) { int n = i >> 7, k = i & 127; w1t[i] = f2bf(W1[k * 256 + n]); }
    for (int i = tid; i < 64 * 256; i += nth) { int n = i >> 8, k = i & 255; w2t[i] = f2bf(W2[k * 64 + n]); }
    for (int i = tid; i < 64 * 64;  i += nth) { int n = i >> 6, k = i & 63;  wqt[i] = f2bf(Wq[k * 64 + n]); }
    if (tid < 32) energy[tid] = 0.f;
}

// ---------------- fused MLP + K=6 iterations + energy ----------------
// One block = 64-row output window, 80-row halo'd compute window (halo 8/side,
// erosion 6 < 8). Hidden dim split in 2 halves of 128 so Zs fits over Qs:
// peak LDS 43.5KB -> 3 blocks/CU. s-channel is removed from the iteration loop
// (s_out = S^6 s_in = fixed 13-tap stencil); only d iterates, with a padded
// conflict-free [2][2][16][68] exchange. A,B regs dropped during GEMM phase,
// reloaded (fp32-exact, L2/L3-warm) for the iterations.
__global__ __launch_bounds__(256, 3) void fused_kernel(
    const float* __restrict__ A, const float* __restrict__ B, const float* __restrict__ Q,
    const float* __restrict__ b1, const float* __restrict__ b2, const float* __restrict__ bq,
    const unsigned short* __restrict__ w1t, const unsigned short* __restrict__ w2t,
    const unsigned short* __restrict__ wqt,
    float* __restrict__ outA, float* __restrict__ outB, float* __restrict__ energy) {
    __shared__ char lds[43584];
    unsigned short* Xs = (unsigned short*)(lds);          // [80][136] bf16 @ [0,21760)
    unsigned short* Qs = (unsigned short*)(lds + 21760);  // [80][72]  bf16 @ [21760,33280)
    unsigned short* Zs = (unsigned short*)(lds + 21760);  // [80][136] bf16 @ [21760,43520) (half-hidden, over Qs after B1)
    _Float16* muS = (_Float16*)(lds);                     // [80][68] fp16 @ [0,10880)   (over Xs after GEMM1h2)
    float* exb = (float*)(lds + 10880);                   // [2][2][16][68] f32 @ [10880,28288) (iter phase)
    float* sS  = (float*)(lds);                           // [80][68] f32 @ [0,21760)    (s phase, over muS/exb)
    float* esm = (float*)(lds + 43520);                   // [4] f32

    const int tid = threadIdx.x;
    const int lane = tid & 63;
    const int w = tid >> 6;       // wave id
    const int q4 = lane >> 4;
    const int l16 = lane & 15;
    const int g = tid >> 4;       // iter layout: row group (5 rows each)
    const int c4 = tid & 15;      // iter layout: col quad
    const int bb = blockIdx.y;
    const int s0 = blockIdx.x * 64;
    const size_t bbase = (size_t)bb * LL;

    // ---- prefetch GEMM3 weights + biases (global, no LDS dep) ----
    short8 wqf[2];
#pragma unroll
    for (int kt = 0; kt < 2; kt++)
        wqf[kt] = *(const short8*)&wqt[(w * 16 + l16) * 64 + kt * 32 + q4 * 8];
    const floatx4 b2q = *(const floatx4*)&b2[w * 16 + q4 * 4];
    const floatx4 bqq = *(const floatx4*)&bq[w * 16 + q4 * 4];

    // ---- phase 1: stage X=[A|B], Q as bf16 (registers discarded) ----
    uint32* Xu = (uint32*)Xs; // row stride 68 uints
    uint32* Qu = (uint32*)Qs; // row stride 36 uints
#pragma unroll
    for (int i = 0; i < 5; i++) {
        int wr = g * 5 + i;
        int gl = (s0 + wr + LL - 8) & (LL - 1); // window starts at s0-8 (circular)
        size_t base = (bbase + gl) * 64 + c4 * 4;
        floatx4 av = *(const floatx4*)(A + base);
        floatx4 bv = *(const floatx4*)(B + base);
        floatx4 qv = *(const floatx4*)(Q + base);
        uint32x2 ua; ua.x = cvtpk(av.x, av.y); ua.y = cvtpk(av.z, av.w);
        uint32x2 ub; ub.x = cvtpk(bv.x, bv.y); ub.y = cvtpk(bv.z, bv.w);
        uint32x2 uq; uq.x = cvtpk(qv.x, qv.y); uq.y = cvtpk(qv.z, qv.w);
        *(uint32x2*)&Xu[wr * 68 + c4 * 2] = ua;
        *(uint32x2*)&Xu[wr * 68 + 32 + c4 * 2] = ub;
        *(uint32x2*)&Qu[wr * 36 + c4 * 2] = uq;
    }
    __syncthreads(); // B0: staging complete

    // ---- GEMM3 (swapped): acc3[nt][r] = gate_pre[row=nt*16+l16][col=w*16+q4*4+r] ----
    floatx4 acc3[5];
#pragma unroll
    for (int nt = 0; nt < 5; nt++) acc3[nt] = (floatx4){0.f, 0.f, 0.f, 0.f};
    __builtin_amdgcn_s_setprio(1);
#pragma unroll
    for (int nt = 0; nt < 5; nt++)
#pragma unroll
        for (int kt = 0; kt < 2; kt++) {
            short8 aq = *(const short8*)&Qs[(nt * 16 + l16) * 72 + kt * 32 + q4 * 8];
            acc3[nt] = __builtin_amdgcn_mfma_f32_16x16x32_bf16(wqf[kt], aq, acc3[nt], 0, 0, 0);
        }
    __builtin_amdgcn_s_setprio(0);
    __syncthreads(); // B1: Qs reads done; Zs may overlay

    // ---- GEMM1/GEMM2 over 2 hidden halves of 128 ----
    floatx4 acc2[5];
#pragma unroll
    for (int nt = 0; nt < 5; nt++) acc2[nt] = (floatx4){0.f, 0.f, 0.f, 0.f};
#pragma unroll
    for (int h = 0; h < 2; h++) {
        // GEMM1 half: Z[:,h*128..h*128+127]; wave owns local cols w*32..w*32+31 (2 ht tiles)
        short8 wf0[4], wf1[4];
#pragma unroll
        for (int kt = 0; kt < 4; kt++) {
            wf0[kt] = *(const short8*)&w1t[(h * 128 + w * 32 + l16) * 128 + kt * 32 + q4 * 8];
            wf1[kt] = *(const short8*)&w1t[(h * 128 + w * 32 + 16 + l16) * 128 + kt * 32 + q4 * 8];
        }
        floatx4 acc0[5], acc1[5];
#pragma unroll
        for (int nt = 0; nt < 5; nt++) {
            acc0[nt] = (floatx4){0.f, 0.f, 0.f, 0.f};
            acc1[nt] = (floatx4){0.f, 0.f, 0.f, 0.f};
        }
        __builtin_amdgcn_s_setprio(1);
#pragma unroll
        for (int kt = 0; kt < 4; kt++)
#pragma unroll
            for (int nt = 0; nt < 5; nt++) {
                short8 xf = *(const short8*)&Xs[(nt * 16 + l16) * 136 + kt * 32 + q4 * 8];
                acc0[nt] = __builtin_amdgcn_mfma_f32_16x16x32_bf16(wf0[kt], xf, acc0[nt], 0, 0, 0);
                acc1[nt] = __builtin_amdgcn_mfma_f32_16x16x32_bf16(wf1[kt], xf, acc1[nt], 0, 0, 0);
            }
        __builtin_amdgcn_s_setprio(0);
        const floatx4 b1q0 = *(const floatx4*)&b1[h * 128 + w * 32 + q4 * 4];
        const floatx4 b1q1 = *(const floatx4*)&b1[h * 128 + w * 32 + 16 + q4 * 4];
#pragma unroll
        for (int nt = 0; nt < 5; nt++) {
            uint32x2 uz;
            uz.x = cvtpk(fmaxf(acc0[nt][0] + b1q0.x, 0.f), fmaxf(acc0[nt][1] + b1q0.y, 0.f));
            uz.y = cvtpk(fmaxf(acc0[nt][2] + b1q0.z, 0.f), fmaxf(acc0[nt][3] + b1q0.w, 0.f));
            *(uint32x2*)&Zs[(nt * 16 + l16) * 136 + w * 32 + q4 * 4] = uz;
            uz.x = cvtpk(fmaxf(acc1[nt][0] + b1q1.x, 0.f), fmaxf(acc1[nt][1] + b1q1.y, 0.f));
            uz.y = cvtpk(fmaxf(acc1[nt][2] + b1q1.z, 0.f), fmaxf(acc1[nt][3] + b1q1.w, 0.f));
            *(uint32x2*)&Zs[(nt * 16 + l16) * 136 + w * 32 + 16 + q4 * 4] = uz;
        }
        // GEMM2 A-frags for this half
        short8 w2f[4];
#pragma unroll
        for (int kt = 0; kt < 4; kt++)
            w2f[kt] = *(const short8*)&w2t[(w * 16 + l16) * 256 + h * 128 + kt * 32 + q4 * 8];
        __syncthreads(); // B2/B4: Zs half complete
        __builtin_amdgcn_s_setprio(1);
#pragma unroll
        for (int nt = 0; nt < 5; nt++)
#pragma unroll
            for (int kt = 0; kt < 4; kt++) {
                short8 az = *(const short8*)&Zs[(nt * 16 + l16) * 136 + kt * 32 + q4 * 8];
                acc2[nt] = __builtin_amdgcn_mfma_f32_16x16x32_bf16(w2f[kt], az, acc2[nt], 0, 0, 0);
            }
        __builtin_amdgcn_s_setprio(0);
        if (h == 0) __syncthreads(); // B3: h1 reads done before h2 overwrites Zs
    }

    // ---- epilogue: mu -> LDS fp16 (muS over dead Xs; disjoint from Zs) ----
#pragma unroll
    for (int nt = 0; nt < 5; nt++) {
        half4 hm;
#pragma unroll
        for (int r = 0; r < 4; r++) {
            float sp = fast_softplus(acc2[nt][r] + ((const float*)&b2q)[r]);
            float gt = fast_tanh(acc3[nt][r] + ((const float*)&bqq)[r]);
            hm[r] = (_Float16)(sp * (1.f + 0.5f * gt));
        }
        *(half4*)&muS[(nt * 16 + l16) * 68 + w * 16 + q4 * 4] = hm;
    }
    __syncthreads(); // B5: mu ready; Zs dead (exb region free)

    // ---- phase 3: reload A,B (fp32-exact); K=6 iterations on d only ----
    floatx4 sv[5], dv[5], fv[5];
#pragma unroll
    for (int i = 0; i < 5; i++) {
        int wr = g * 5 + i;
        int gl = (s0 + wr + LL - 8) & (LL - 1);
        size_t base = (bbase + gl) * 64 + c4 * 4;
        floatx4 av = *(const floatx4*)(A + base);
        floatx4 bv = *(const floatx4*)(B + base);
        sv[i] = av + bv;
        dv[i] = av - bv;
        half4 m4 = *(const half4*)&muS[wr * 68 + c4 * 4];
        fv[i] = 1.f - (2.f * ETA) * __builtin_convertvector(m4, floatx4);
    }
#define EXD(p, t, gg) (exb + (((p) * 2 + (t)) * 16 + (gg)) * 68 + c4 * 4)
    for (int it = 0; it < 6; it++) {
#pragma unroll
        for (int i = 0; i < 5; i++) dv[i] *= fv[i];
        const int p = it & 1;
        *(floatx4*)EXD(p, 0, g) = dv[0];
        *(floatx4*)EXD(p, 1, g) = dv[4];
        __syncthreads();
        floatx4 dUp = (g > 0)  ? *(const floatx4*)EXD(p, 1, g - 1) : dv[0];
        floatx4 dDn = (g < 15) ? *(const floatx4*)EXD(p, 0, g + 1) : dv[4];
        floatx4 prev = dUp, cur = dv[0];
#pragma unroll
        for (int i = 0; i < 5; i++) {
            floatx4 nxt = (i < 4) ? dv[i + 1] : dDn;
            dv[i] = cur - LAM * (2.f * cur - prev - nxt);
            prev = cur; cur = nxt;
        }
    }
#undef EXD
    // ---- energy partial (needs fv, final dv) ----
    float e = 0.f;
#pragma unroll
    for (int i = 0; i < 5; i++) {
        int wr = g * 5 + i;
        if (wr >= 8 && wr < 72) {
            floatx4 d = dv[i];
            floatx4 qv = (1.f - fv[i]) * d * d; // (1-f) = 2*eta*mu
            e += qv.x + qv.y + qv.z + qv.w;
        }
    }
    e *= 0.25f / ETA; // 0.5 * sum(mu * d^2)

    // ---- s channel: s_out = S^6 s_in, direct 13-tap over LDS ----
    __syncthreads(); // B6: exb reads done; sS may overlay
#pragma unroll
    for (int i = 0; i < 5; i++)
        *(floatx4*)&sS[(g * 5 + i) * 68 + c4 * 4] = sv[i];
    __syncthreads(); // B7: s staged
    floatx4 srow[17];
    const int sbase = g * 5 - 6;
#pragma unroll
    for (int j = 0; j < 17; j++) {
        int rr = min(max(sbase + j, 0), 79); // clamped loads unused by guarded outputs
        srow[j] = *(const floatx4*)&sS[rr * 68 + c4 * 4];
    }
#pragma unroll
    for (int i = 0; i < 5; i++) {
        floatx4 sm = SC0 * srow[i + 6];
        sm += SC1 * (srow[i + 5] + srow[i + 7]);
        sm += SC2 * (srow[i + 4] + srow[i + 8]);
        sm += SC3 * (srow[i + 3] + srow[i + 9]);
        sm += SC4 * (srow[i + 2] + srow[i + 10]);
        sm += SC5 * (srow[i + 1] + srow[i + 11]);
        sm += SC6 * (srow[i + 0] + srow[i + 12]);
        sv[i] = sm;
    }

    // ---- store interior rows (window rows 8..71) ----
#pragma unroll
    for (int i = 0; i < 5; i++) {
        int wr = g * 5 + i;
        if (wr >= 8 && wr < 72) {
            size_t gidx = (bbase + s0 + (wr - 8)) * 64 + c4 * 4;
            *(floatx4*)(outA + gidx) = (sv[i] + dv[i]) * 0.5f;
            *(floatx4*)(outB + gidx) = (sv[i] - dv[i]) * 0.5f;
        }
    }
#pragma unroll
    for (int off = 32; off > 0; off >>= 1) e += __shfl_down(e, off, 64);
    if ((tid & 63) == 0) esm[tid >> 6] = e;
    __syncthreads();
    if (tid == 0) atomicAdd(energy + bb, esm[0] + esm[1] + esm[2] + esm[3]);
}

extern "C" void kernel_launch(void* const* d_in, const int* in_sizes, int n_in,
                              void* d_out, int out_size, void* d_ws, size_t ws_size,
                              hipStream_t stream) {
    const float* A  = (const float*)d_in[0];
    const float* B  = (const float*)d_in[1];
    const float* Q  = (const float*)d_in[2];
    const float* W1 = (const float*)d_in[3];
    const float* b1 = (const float*)d_in[4];
    const float* W2 = (const float*)d_in[5];
    const float* b2 = (const float*)d_in[6];
    const float* Wq = (const float*)d_in[7];
    const float* bq = (const float*)d_in[8];

    float* outA = (float*)d_out;
    float* outB = outA + (size_t)RTOT * 64;
    float* energy = outB + (size_t)RTOT * 64;

    char* ws = (char*)d_ws;
    unsigned short* w1t = (unsigned short*)(ws + W1T_OFF);
    unsigned short* w2t = (unsigned short*)(ws + W2T_OFF);
    unsigned short* wqt = (unsigned short*)(ws + WQT_OFF);

    hipLaunchKernelGGL(prep_kernel, dim3(64), dim3(256), 0, stream,
                       W1, W2, Wq, w1t, w2t, wqt, energy);
    hipLaunchKernelGGL(fused_kernel, dim3(LL / 64, BSZ), dim3(256), 0, stream,
                       A, B, Q, b1, b2, bq, w1t, w2t, wqt, outA, outB, energy);
}